// Round 8
// baseline (270.410 us; speedup 1.0000x reference)
//
#include <hip/hip_runtime.h>
#include <hip/hip_bf16.h>
#include <cstdint>
#include <cstddef>

// ---------- types & helpers ----------
typedef __bf16 bf16x8 __attribute__((ext_vector_type(8)));
typedef float f32x4 __attribute__((ext_vector_type(4)));
typedef unsigned short u16;
typedef unsigned short u16x8 __attribute__((ext_vector_type(8)));
typedef unsigned int u32;

typedef __attribute__((address_space(1))) void gvoid_t;
typedef __attribute__((address_space(3))) void lvoid_t;

// async global->LDS, 16B per lane. LDS dest = wave-uniform base + lane*16.
__device__ __forceinline__ void gld_lds16(const void* g, void* l) {
  __builtin_amdgcn_global_load_lds((gvoid_t*)g, (lvoid_t*)l, 16, 0, 0);
}

__device__ __forceinline__ u16 f2bf(float f) {
  u32 u = __float_as_uint(f);
  u += 0x7fffu + ((u >> 16) & 1u);   // RNE
  return (u16)(u >> 16);
}
// packed f32x2 -> bf16x2 (v_cvt_pk_bf16_f32 via HIP header; memcpy punning)
__device__ __forceinline__ u32 pack2(float a, float b) {
  __hip_bfloat162 h = __float22bfloat162_rn(float2{a, b});
  u32 r;
  __builtin_memcpy(&r, &h, 4);
  return r;
}
__device__ __forceinline__ bf16x8 ld_frag(const u16* p) {
  return __builtin_bit_cast(bf16x8, *(const uint4*)p);
}
__device__ __forceinline__ f32x4 mfma16(bf16x8 a, bf16x8 b, f32x4 c) {
  return __builtin_amdgcn_mfma_f32_16x16x32_bf16(a, b, c, 0, 0, 0);
}
// 2^x via v_exp_f32 (single instruction)
__device__ __forceinline__ float ex2(float x) {
  return __builtin_amdgcn_exp2f(x);
}

#define D_MODEL 1024
#define SEQ     2048
#define NHEAD   16
// 1/sqrt(HEAD) * log2(e): folded into Wq/bq so QK^T scores are in exp2 domain
#define QSC     0.1803368801f
#define MBIAS   (-1.4426950408e9f)   // -1e9 * log2(e)

// ---------- fp32 -> bf16 conversion (x, y, Wq(scaled), Wk, Wv) ----------
__global__ __launch_bounds__(256) void cvt_kernel(
    const float* __restrict__ x,  const float* __restrict__ y,
    const float* __restrict__ wq, const float* __restrict__ wk,
    const float* __restrict__ wv,
    u16* __restrict__ xb, u16* __restrict__ yb,
    u16* __restrict__ wqb, u16* __restrict__ wkb, u16* __restrict__ wvb) {
  const int t = blockIdx.y;
  const float* src;
  u16* dst;
  int n;
  float sc = 1.0f;
  if (t == 0)      { src = x;  dst = xb;  n = 4096 * 1024; }
  else if (t == 1) { src = y;  dst = yb;  n = 4096 * 1024; }
  else if (t == 2) { src = wq; dst = wqb; n = 1024 * 1024; sc = QSC; }
  else if (t == 3) { src = wk; dst = wkb; n = 1024 * 1024; }
  else             { src = wv; dst = wvb; n = 1024 * 1024; }
  const int i = (blockIdx.x * 256 + threadIdx.x) * 8;
  if (i >= n) return;
  const float4 a = *(const float4*)(src + i);
  const float4 b = *(const float4*)(src + i + 4);
  ushort4 lo, hi;
  lo.x = f2bf(a.x * sc); lo.y = f2bf(a.y * sc); lo.z = f2bf(a.z * sc); lo.w = f2bf(a.w * sc);
  hi.x = f2bf(b.x * sc); hi.y = f2bf(b.y * sc); hi.z = f2bf(b.z * sc); hi.w = f2bf(b.w * sc);
  *(ushort4*)(dst + i) = lo;
  *(ushort4*)(dst + i + 4) = hi;
}

// ---------- prep (post-qkv): mask->biasC bf16 [b][q][kv], Wo->bf16 ----------
__global__ __launch_bounds__(256) void prep_kernel(
    const float* __restrict__ mask, const float* __restrict__ wo,
    u16* __restrict__ biasC, u16* __restrict__ wob) {
  const int bid = blockIdx.x;
  if (bid < 4096) {   // mask: 2*2048*2048 fp32 = 8M elems
    const int i = (bid * 256 + threadIdx.x) * 8;
    const float4 a = *(const float4*)(mask + i);
    const float4 b = *(const float4*)(mask + i + 4);
    ushort4 lo, hi;
    lo.x = f2bf(MBIAS - a.x * MBIAS); lo.y = f2bf(MBIAS - a.y * MBIAS);
    lo.z = f2bf(MBIAS - a.z * MBIAS); lo.w = f2bf(MBIAS - a.w * MBIAS);
    hi.x = f2bf(MBIAS - b.x * MBIAS); hi.y = f2bf(MBIAS - b.y * MBIAS);
    hi.z = f2bf(MBIAS - b.z * MBIAS); hi.w = f2bf(MBIAS - b.w * MBIAS);
    *(ushort4*)(biasC + i) = lo;
    *(ushort4*)(biasC + i + 4) = hi;
  } else {            // Wo: 1M elems, 512 blocks
    const int i = ((bid - 4096) * 256 + threadIdx.x) * 8;
    const float4 a = *(const float4*)(wo + i);
    const float4 b = *(const float4*)(wo + i + 4);
    ushort4 lo, hi;
    lo.x = f2bf(a.x); lo.y = f2bf(a.y); lo.z = f2bf(a.z); lo.w = f2bf(a.w);
    hi.x = f2bf(b.x); hi.y = f2bf(b.y); hi.z = f2bf(b.z); hi.w = f2bf(b.w);
    *(ushort4*)(wob + i) = lo;
    *(ushort4*)(wob + i + 4) = hi;
  }
}

// ---------- 128x128 BK=64 gemm_bt block (D = A @ W^T + bias*bscale) ----------
// MODE 0: D bf16 row-major [M,1024]; MODE 1: D fp32 row-major;
// MODE 2: D = vt, bf16 transposed [(b*16+h)*64+d][s] via LDS transpose epilogue.
template <int MODE, typename OT>
__device__ __forceinline__ void gemm_block_128(const u16* __restrict__ A,
                                               const u16* __restrict__ W,
                                               const float* __restrict__ bias,
                                               float bscale,
                                               OT* __restrict__ D,
                                               int mb, int nb) {
  __shared__ __align__(16) u16 S[16384];     // Asl(8K u16) + Bsl(8K u16)
  u16* Asl = S;
  u16* Bsl = S + 8192;
  const int tid = threadIdx.x;
  const int w = tid >> 6, lane = tid & 63, quad = lane >> 4, l16 = lane & 15;
  const int wm = (w & 1) * 64, wn = (w >> 1) * 64;
  const int cidx = w * 64 + lane;

  f32x4 acc[4][4];
#pragma unroll
  for (int i = 0; i < 4; ++i)
#pragma unroll
    for (int j = 0; j < 4; ++j) acc[i][j] = f32x4{0.f, 0.f, 0.f, 0.f};

  for (int k0 = 0; k0 < 1024; k0 += 64) {
    __syncthreads();
#pragma unroll
    for (int t = 0; t < 4; ++t) {
      const int idx = t * 256 + cidx;          // 16B-chunk id, 0..1023
      const int row = idx >> 3;                // 8 chunks per 64-elem row
      const int g = (idx & 7) ^ (row & 7);     // swizzled source chunk
      const size_t dst = (size_t)(t * 4 + w) * 1024;
      gld_lds16(A + (size_t)(mb * 128 + row) * 1024 + k0 + g * 8, (char*)Asl + dst);
      gld_lds16(W + (size_t)(nb * 128 + row) * 1024 + k0 + g * 8, (char*)Bsl + dst);
    }
    __syncthreads();

#pragma unroll
    for (int kk = 0; kk < 2; ++kk) {
      bf16x8 af[4], bfr[4];
#pragma unroll
      for (int i = 0; i < 4; ++i) {
        const int ar = wm + i * 16 + l16;
        const int br = wn + i * 16 + l16;
        af[i]  = ld_frag(Asl + ar * 64 + (((kk * 4 + quad) ^ (ar & 7)) * 8));
        bfr[i] = ld_frag(Bsl + br * 64 + (((kk * 4 + quad) ^ (br & 7)) * 8));
      }
#pragma unroll
      for (int i = 0; i < 4; ++i)
#pragma unroll
        for (int j = 0; j < 4; ++j) acc[i][j] = mfma16(af[i], bfr[j], acc[i][j]);
    }
  }

  if constexpr (MODE == 2) {
    // transposed epilogue: acc tile [128 s][128 d] -> LDS [d][s] -> vt rows
    __syncthreads();   // all waves done with Asl/Bsl frag reads
#pragma unroll
    for (int i = 0; i < 4; ++i)
#pragma unroll
      for (int j = 0; j < 4; ++j) {
        const int dl = wn + j * 16 + l16;
        const float bv = bias[nb * 128 + dl];
        const int sx = (wm + i * 16 + quad * 4) ^ ((dl & 15) << 3);
        uint2 pv;
        pv.x = (u32)f2bf(acc[i][j][0] + bv) | ((u32)f2bf(acc[i][j][1] + bv) << 16);
        pv.y = (u32)f2bf(acc[i][j][2] + bv) | ((u32)f2bf(acc[i][j][3] + bv) << 16);
        *(uint2*)(S + dl * 128 + sx) = pv;
      }
    __syncthreads();
    const int dl = tid >> 1, half = tid & 1;
    const int bb = mb >> 4, s0 = (mb & 15) * 128;
    u16* vrow = (u16*)D + (size_t)(bb * 1024 + nb * 128 + dl) * SEQ + s0 + half * 64;
#pragma unroll
    for (int c = 0; c < 8; ++c) {
      const int pc = (half * 8 + c) ^ (dl & 15);
      *(uint4*)(vrow + c * 8) = *(const uint4*)(S + dl * 128 + pc * 8);
    }
  } else {
    // epilogue: C/D layout col=lane&15, row=quad*4+r  [verified m89/m91]
#pragma unroll
    for (int i = 0; i < 4; ++i)
#pragma unroll
      for (int j = 0; j < 4; ++j) {
        const int gn = nb * 128 + wn + j * 16 + l16;
        const float bv = bias[gn] * bscale;
#pragma unroll
        for (int r = 0; r < 4; ++r) {
          const int gm = mb * 128 + wm + i * 16 + quad * 4 + r;
          const float v = acc[i][j][r] + bv;
          if constexpr (sizeof(OT) == 2)
            D[(size_t)gm * 1024 + gn] = (OT)f2bf(v);
          else
            D[(size_t)gm * 1024 + gn] = (OT)v;
        }
      }
  }
}

__global__ __launch_bounds__(256) void qkv_kernel(
    const u16* __restrict__ xb, const u16* __restrict__ yb,
    const u16* __restrict__ Wqb, const u16* __restrict__ Wkb, const u16* __restrict__ Wvb,
    const float* __restrict__ bq, const float* __restrict__ bk, const float* __restrict__ bv,
    u16* __restrict__ qb, u16* __restrict__ kb, u16* __restrict__ vt) {
  const int mat = blockIdx.y >> 3;
  const int nb = blockIdx.y & 7;
  const int mb = blockIdx.x;
  if (mat == 0)      gemm_block_128<0, u16>(xb, Wqb, bq, QSC,  qb, mb, nb);
  else if (mat == 1) gemm_block_128<0, u16>(yb, Wkb, bk, 1.0f, kb, mb, nb);
  else               gemm_block_128<2, u16>(yb, Wvb, bv, 1.0f, vt, mb, nb);
}

__global__ __launch_bounds__(256) void oproj_kernel(
    const u16* __restrict__ ctx, const u16* __restrict__ Wob,
    const float* __restrict__ bo, float* __restrict__ out) {
  gemm_block_128<1, float>(ctx, Wob, bo, 1.0f, out, blockIdx.x, blockIdx.y);
}

// ---------- flash attention: 4 waves x 32 q-rows (128 q/block), KV tile = 64 ----
// Computes S^T (A=K, B=Q): lane's 4 C-values are 4 consecutive kv at one q ->
// b64 P-stores in [q][kv] layout; bias tile is [q][kv] (original mask
// orientation). No running max (scores bounded, exp2 domain; masked ->
// 2^-1.4e9 = 0). Row-sum via MFMA ones-column.
__global__ __launch_bounds__(256) void attn_kernel(
    const u16* __restrict__ qb, const u16* __restrict__ kb,
    const u16* __restrict__ vt, const u16* __restrict__ biasC,
    u16* __restrict__ ctx) {
  const int h = blockIdx.x;
  const int qblk = blockIdx.y;
  const int b = blockIdx.z;
  const int tid = threadIdx.x, w = tid >> 6, lane = tid & 63;
  const int quad = lane >> 4, l16 = lane & 15;
  const int q0 = qblk * 128;

  __shared__ __align__(16) u16 Ks[64 * 64];     // [kv][d]   swizzled rows
  __shared__ __align__(16) u16 Vs[64 * 64];     // [d][kv]   swizzled rows
  __shared__ __align__(16) u16 Bs[128 * 64];    // bias [q][kv] swizzled rows
  __shared__ __align__(16) u16 Ps[4 * 32 * 64]; // per-wave P [q 32][kv 64] swizzled

  const int qbase = w * 32;
  // Q B-frags: lane n=l16 holds Q row (q0+qbase+f*16+l16), k over d
  bf16x8 qf[2][2];
#pragma unroll
  for (int f = 0; f < 2; ++f) {
    const u16* qp = qb + (size_t)(b * SEQ + q0 + qbase + f * 16 + l16) * D_MODEL + h * 64;
    qf[f][0] = ld_frag(qp + quad * 8);
    qf[f][1] = ld_frag(qp + 32 + quad * 8);
  }
  // ones B-frag: row n==0 all 1.0 -> lane l16==0 holds ones
  bf16x8 onesf;
  {
    u16x8 t;
    const u16 ov = (l16 == 0) ? (u16)0x3F80 : (u16)0;
#pragma unroll
    for (int j = 0; j < 8; ++j) t[j] = ov;
    onesf = __builtin_bit_cast(bf16x8, t);
  }

  f32x4 O[2][4];
#pragma unroll
  for (int f = 0; f < 2; ++f)
#pragma unroll
    for (int dt = 0; dt < 4; ++dt) O[f][dt] = f32x4{0.f, 0.f, 0.f, 0.f};
  f32x4 O4[2] = {f32x4{0.f, 0.f, 0.f, 0.f}, f32x4{0.f, 0.f, 0.f, 0.f}};

  const int cidx = w * 64 + lane;
  u16* Pw = Ps + w * 2048;

  for (int kt = 0; kt < 32; ++kt) {
    const int kv0 = kt * 64;

    __syncthreads();   // prior iteration's LDS reads complete
#pragma unroll
    for (int t = 0; t < 2; ++t) {
      const int idx = t * 256 + cidx;   // chunk 0..511
      const int row = idx >> 3;
      const int g = (idx & 7) ^ (row & 7);
      const size_t dst = (size_t)(t * 4 + w) * 1024;
      gld_lds16(kb + (size_t)(b * SEQ + kv0 + row) * D_MODEL + h * 64 + g * 8,
                (char*)Ks + dst);
      gld_lds16(vt + ((size_t)((b * NHEAD + h) * 64 + row)) * SEQ + kv0 + g * 8,
                (char*)Vs + dst);
    }
#pragma unroll
    for (int t = 0; t < 4; ++t) {
      const int idx = t * 256 + cidx;   // chunk 0..1023
      const int row = idx >> 3;         // q-local 0..127
      const int g = (idx & 7) ^ (row & 7);
      gld_lds16(biasC + (size_t)(b * SEQ + q0 + row) * SEQ + kv0 + g * 8,
                (char*)Bs + (size_t)(t * 4 + w) * 1024);
    }
    __syncthreads();

    // S^T = K Q^T + bias; p = 2^S; b64 store into P[q][kv]
#pragma unroll
    for (int nt = 0; nt < 4; ++nt) {
      const int kvl = nt * 16 + l16;
      const bf16x8 kf0 = ld_frag(Ks + kvl * 64 + ((quad ^ (kvl & 7)) * 8));
      const bf16x8 kf1 = ld_frag(Ks + kvl * 64 + (((4 + quad) ^ (kvl & 7)) * 8));
#pragma unroll
      for (int f = 0; f < 2; ++f) {
        const int br = qbase + f * 16 + l16;              // bias row (q-local)
        const int ck = nt * 2 + (quad >> 1);              // kv chunk
        const uint2 bw = *(const uint2*)(Bs + br * 64 + ((ck ^ (br & 7)) * 8) + (quad & 1) * 4);
        f32x4 z;
        z[0] = __uint_as_float(bw.x << 16);
        z[1] = __uint_as_float(bw.x & 0xffff0000u);
        z[2] = __uint_as_float(bw.y << 16);
        z[3] = __uint_as_float(bw.y & 0xffff0000u);
        z = mfma16(kf0, qf[f][0], z);
        z = mfma16(kf1, qf[f][1], z);
        uint2 pv;
        pv.x = pack2(ex2(z[0]), ex2(z[1]));
        pv.y = pack2(ex2(z[2]), ex2(z[3]));
        const int pr = f * 16 + l16;                      // P row (q-local in wave)
        *(uint2*)(Pw + pr * 64 + ((ck ^ (pr & 7)) * 8) + (quad & 1) * 4) = pv;
      }
    }

    // P A-frags, then O += P V ; l += P * ones
    bf16x8 pf[2][2];
#pragma unroll
    for (int f = 0; f < 2; ++f) {
      const int pr = f * 16 + l16;
      pf[f][0] = ld_frag(Pw + pr * 64 + ((quad ^ (pr & 7)) * 8));
      pf[f][1] = ld_frag(Pw + pr * 64 + (((4 + quad) ^ (pr & 7)) * 8));
    }
#pragma unroll
    for (int dt = 0; dt < 4; ++dt) {
      const int vr = dt * 16 + l16;
      const bf16x8 vf0 = ld_frag(Vs + vr * 64 + ((quad ^ (vr & 7)) * 8));
      const bf16x8 vf1 = ld_frag(Vs + vr * 64 + (((4 + quad) ^ (vr & 7)) * 8));
#pragma unroll
      for (int f = 0; f < 2; ++f) {
        O[f][dt] = mfma16(pf[f][0], vf0, O[f][dt]);
        O[f][dt] = mfma16(pf[f][1], vf1, O[f][dt]);
      }
    }
#pragma unroll
    for (int f = 0; f < 2; ++f) {
      O4[f] = mfma16(pf[f][0], onesf, O4[f]);
      O4[f] = mfma16(pf[f][1], onesf, O4[f]);
    }
  }

  // l in col-0 lanes of each quad; epilogue ctx[b,q,h*64+d] = O / l
  float inv[2][4];
#pragma unroll
  for (int f = 0; f < 2; ++f)
#pragma unroll
    for (int r = 0; r < 4; ++r)
      inv[f][r] = 1.0f / __shfl(O4[f][r], lane & 48, 64);

#pragma unroll
  for (int f = 0; f < 2; ++f)
#pragma unroll
    for (int dt = 0; dt < 4; ++dt)
#pragma unroll
      for (int r = 0; r < 4; ++r) {
        const int gq = b * SEQ + q0 + qbase + f * 16 + quad * 4 + r;
        const int gd = h * 64 + dt * 16 + l16;
        ctx[(size_t)gq * D_MODEL + gd] = f2bf(O[f][dt][r] * inv[f][r]);
      }
}

// ---------- host ----------
extern "C" void kernel_launch(void* const* d_in, const int* in_sizes, int n_in,
                              void* d_out, int out_size, void* d_ws, size_t ws_size,
                              hipStream_t stream) {
  (void)in_sizes; (void)n_in; (void)out_size; (void)ws_size;
  const float* x    = (const float*)d_in[0];
  const float* y    = (const float*)d_in[1];
  const float* mask = (const float*)d_in[2];
  const float* Wq   = (const float*)d_in[3];
  const float* bq   = (const float*)d_in[4];
  const float* Wk   = (const float*)d_in[5];
  const float* bk   = (const float*)d_in[6];
  const float* Wv   = (const float*)d_in[7];
  const float* bv   = (const float*)d_in[8];
  const float* Wo   = (const float*)d_in[9];
  const float* bo   = (const float*)d_in[10];
  float* out = (float*)d_out;

  // 56 MB workspace (round-2-proven footprint), aliased by lifetime.
  const size_t M4 = (size_t)4096 * 1024;   // 4M u16 = 8 MB
  const size_t M1 = (size_t)1024 * 1024;   // 1M u16 = 2 MB
  u16* qbuf  = (u16*)d_ws;         // [0,8)   qkv -> attn
  u16* kbuf  = qbuf + M4;          // [8,16)  qkv -> attn
  u16* vt    = kbuf + M4;          // [16,24) qkv (transposed) -> attn
  u16* cbuf  = vt + M4;            // [24,32) attn -> oproj
  u16* wob   = cbuf + M4;          // [32,34) prep -> oproj
  u16* xb    = wob + M1;           // [34,42) cvt -> qkv (dead after)
  u16* yb    = xb + M4;            // [42,50) cvt -> qkv (dead after)
  u16* wqb   = yb + M4;            // [50,52) cvt -> qkv
  u16* wkb   = wqb + M1;           // [52,54)
  u16* wvb   = wkb + M1;           // [54,56)
  u16* biasC = xb;                 // 16 MB over xb+yb (written by prep, post-qkv)

  cvt_kernel<<<dim3(2048, 5, 1), 256, 0, stream>>>(x, y, Wq, Wk, Wv,
                                                   xb, yb, wqb, wkb, wvb);
  qkv_kernel<<<dim3(32, 24, 1), 256, 0, stream>>>(xb, yb, wqb, wkb, wvb,
                                                  bq, bk, bv, qbuf, kbuf, vt);
  prep_kernel<<<dim3(4608, 1, 1), 256, 0, stream>>>(mask, Wo, biasC, wob);
  attn_kernel<<<dim3(NHEAD, 16, 2), 256, 0, stream>>>(qbuf, kbuf, vt, biasC, cbuf);
  oproj_kernel<<<dim3(32, 8, 1), 256, 0, stream>>>(cbuf, wob, bo, out);
}

// Round 9
// 264.493 us; speedup vs baseline: 1.0224x; 1.0224x over previous
//
#include <hip/hip_runtime.h>
#include <cstdint>
#include <cstddef>

// ---------- types & helpers ----------
typedef __bf16 bf16x8 __attribute__((ext_vector_type(8)));
typedef float f32x4 __attribute__((ext_vector_type(4)));
typedef unsigned short u16;
typedef unsigned short u16x8 __attribute__((ext_vector_type(8)));
typedef unsigned int u32;

typedef __attribute__((address_space(1))) void gvoid_t;
typedef __attribute__((address_space(3))) void lvoid_t;

// async global->LDS, 16B per lane. LDS dest = wave-uniform base + lane*16.
__device__ __forceinline__ void gld_lds16(const void* g, void* l) {
  __builtin_amdgcn_global_load_lds((gvoid_t*)g, (lvoid_t*)l, 16, 0, 0);
}

__device__ __forceinline__ u16 f2bf(float f) {
  u32 u = __float_as_uint(f);
  u += 0x7fffu + ((u >> 16) & 1u);   // RNE
  return (u16)(u >> 16);
}
// packed f32x2 -> bf16x2 via v_perm_b32, half-up rounding: 3 VALU ops total
__device__ __forceinline__ u32 pack_rnd(float a, float b) {
  const u32 ua = __float_as_uint(a) + 0x8000u;
  const u32 ub = __float_as_uint(b) + 0x8000u;
  return __builtin_amdgcn_perm(ub, ua, 0x07060302u);  // [ub.hi16 : ua.hi16]
}
__device__ __forceinline__ bf16x8 ld_frag(const u16* p) {
  return __builtin_bit_cast(bf16x8, *(const uint4*)p);
}
__device__ __forceinline__ f32x4 mfma16(bf16x8 a, bf16x8 b, f32x4 c) {
  return __builtin_amdgcn_mfma_f32_16x16x32_bf16(a, b, c, 0, 0, 0);
}
// 2^x via v_exp_f32 (single instruction)
__device__ __forceinline__ float ex2(float x) {
  return __builtin_amdgcn_exp2f(x);
}

#define D_MODEL 1024
#define SEQ     2048
#define NHEAD   16
// 1/sqrt(HEAD) * log2(e): folded into Wq/bq so QK^T scores are in exp2 domain
#define QSC     0.1803368801f
#define MBIAS   (-1.4426950408e9f)   // -1e9 * log2(e)

// ---------- fp32 -> bf16 conversion (x, y, Wq(scaled), Wk, Wv) ----------
__global__ __launch_bounds__(256) void cvt_kernel(
    const float* __restrict__ x,  const float* __restrict__ y,
    const float* __restrict__ wq, const float* __restrict__ wk,
    const float* __restrict__ wv,
    u16* __restrict__ xb, u16* __restrict__ yb,
    u16* __restrict__ wqb, u16* __restrict__ wkb, u16* __restrict__ wvb) {
  const int t = blockIdx.y;
  const float* src;
  u16* dst;
  int n;
  float sc = 1.0f;
  if (t == 0)      { src = x;  dst = xb;  n = 4096 * 1024; }
  else if (t == 1) { src = y;  dst = yb;  n = 4096 * 1024; }
  else if (t == 2) { src = wq; dst = wqb; n = 1024 * 1024; sc = QSC; }
  else if (t == 3) { src = wk; dst = wkb; n = 1024 * 1024; }
  else             { src = wv; dst = wvb; n = 1024 * 1024; }
  const int i = (blockIdx.x * 256 + threadIdx.x) * 8;
  if (i >= n) return;
  const float4 a = *(const float4*)(src + i);
  const float4 b = *(const float4*)(src + i + 4);
  ushort4 lo, hi;
  lo.x = f2bf(a.x * sc); lo.y = f2bf(a.y * sc); lo.z = f2bf(a.z * sc); lo.w = f2bf(a.w * sc);
  hi.x = f2bf(b.x * sc); hi.y = f2bf(b.y * sc); hi.z = f2bf(b.z * sc); hi.w = f2bf(b.w * sc);
  *(ushort4*)(dst + i) = lo;
  *(ushort4*)(dst + i + 4) = hi;
}

// ---------- prep (post-qkv): mask->biasC bf16 [b][q][kv], Wo->bf16 ----------
__global__ __launch_bounds__(256) void prep_kernel(
    const float* __restrict__ mask, const float* __restrict__ wo,
    u16* __restrict__ biasC, u16* __restrict__ wob) {
  const int bid = blockIdx.x;
  if (bid < 4096) {   // mask: 2*2048*2048 fp32 = 8M elems
    const int i = (bid * 256 + threadIdx.x) * 8;
    const float4 a = *(const float4*)(mask + i);
    const float4 b = *(const float4*)(mask + i + 4);
    ushort4 lo, hi;
    lo.x = f2bf(MBIAS - a.x * MBIAS); lo.y = f2bf(MBIAS - a.y * MBIAS);
    lo.z = f2bf(MBIAS - a.z * MBIAS); lo.w = f2bf(MBIAS - a.w * MBIAS);
    hi.x = f2bf(MBIAS - b.x * MBIAS); hi.y = f2bf(MBIAS - b.y * MBIAS);
    hi.z = f2bf(MBIAS - b.z * MBIAS); hi.w = f2bf(MBIAS - b.w * MBIAS);
    *(ushort4*)(biasC + i) = lo;
    *(ushort4*)(biasC + i + 4) = hi;
  } else {            // Wo: 1M elems, 512 blocks
    const int i = ((bid - 4096) * 256 + threadIdx.x) * 8;
    const float4 a = *(const float4*)(wo + i);
    const float4 b = *(const float4*)(wo + i + 4);
    ushort4 lo, hi;
    lo.x = f2bf(a.x); lo.y = f2bf(a.y); lo.z = f2bf(a.z); lo.w = f2bf(a.w);
    hi.x = f2bf(b.x); hi.y = f2bf(b.y); hi.z = f2bf(b.z); hi.w = f2bf(b.w);
    *(ushort4*)(wob + i) = lo;
    *(ushort4*)(wob + i + 4) = hi;
  }
}

// ---------- 128x128 BK=64 gemm_bt block (D = A @ W^T + bias*bscale) ----------
// MODE 0: D bf16 row-major [M,1024]; MODE 1: D fp32 row-major;
// MODE 2: D = vt, bf16 transposed [(b*16+h)*64+d][s] via LDS transpose epilogue.
template <int MODE, typename OT>
__device__ __forceinline__ void gemm_block_128(const u16* __restrict__ A,
                                               const u16* __restrict__ W,
                                               const float* __restrict__ bias,
                                               float bscale,
                                               OT* __restrict__ D,
                                               int mb, int nb) {
  __shared__ __align__(16) u16 S[16384];     // Asl(8K u16) + Bsl(8K u16)
  u16* Asl = S;
  u16* Bsl = S + 8192;
  const int tid = threadIdx.x;
  const int w = tid >> 6, lane = tid & 63, quad = lane >> 4, l16 = lane & 15;
  const int wm = (w & 1) * 64, wn = (w >> 1) * 64;
  const int cidx = w * 64 + lane;

  f32x4 acc[4][4];
#pragma unroll
  for (int i = 0; i < 4; ++i)
#pragma unroll
    for (int j = 0; j < 4; ++j) acc[i][j] = f32x4{0.f, 0.f, 0.f, 0.f};

  for (int k0 = 0; k0 < 1024; k0 += 64) {
    __syncthreads();
#pragma unroll
    for (int t = 0; t < 4; ++t) {
      const int idx = t * 256 + cidx;          // 16B-chunk id, 0..1023
      const int row = idx >> 3;                // 8 chunks per 64-elem row
      const int g = (idx & 7) ^ (row & 7);     // swizzled source chunk
      const size_t dst = (size_t)(t * 4 + w) * 1024;
      gld_lds16(A + (size_t)(mb * 128 + row) * 1024 + k0 + g * 8, (char*)Asl + dst);
      gld_lds16(W + (size_t)(nb * 128 + row) * 1024 + k0 + g * 8, (char*)Bsl + dst);
    }
    __syncthreads();

#pragma unroll
    for (int kk = 0; kk < 2; ++kk) {
      bf16x8 af[4], bfr[4];
#pragma unroll
      for (int i = 0; i < 4; ++i) {
        const int ar = wm + i * 16 + l16;
        const int br = wn + i * 16 + l16;
        af[i]  = ld_frag(Asl + ar * 64 + (((kk * 4 + quad) ^ (ar & 7)) * 8));
        bfr[i] = ld_frag(Bsl + br * 64 + (((kk * 4 + quad) ^ (br & 7)) * 8));
      }
#pragma unroll
      for (int i = 0; i < 4; ++i)
#pragma unroll
        for (int j = 0; j < 4; ++j) acc[i][j] = mfma16(af[i], bfr[j], acc[i][j]);
    }
  }

  if constexpr (MODE == 2) {
    // transposed epilogue: acc tile [128 s][128 d] -> LDS [d][s] -> vt rows
    __syncthreads();   // all waves done with Asl/Bsl frag reads
#pragma unroll
    for (int i = 0; i < 4; ++i)
#pragma unroll
      for (int j = 0; j < 4; ++j) {
        const int dl = wn + j * 16 + l16;
        const float bv = bias[nb * 128 + dl];
        const int sx = (wm + i * 16 + quad * 4) ^ ((dl & 15) << 3);
        uint2 pv;
        pv.x = (u32)f2bf(acc[i][j][0] + bv) | ((u32)f2bf(acc[i][j][1] + bv) << 16);
        pv.y = (u32)f2bf(acc[i][j][2] + bv) | ((u32)f2bf(acc[i][j][3] + bv) << 16);
        *(uint2*)(S + dl * 128 + sx) = pv;
      }
    __syncthreads();
    const int dl = tid >> 1, half = tid & 1;
    const int bb = mb >> 4, s0 = (mb & 15) * 128;
    u16* vrow = (u16*)D + (size_t)(bb * 1024 + nb * 128 + dl) * SEQ + s0 + half * 64;
#pragma unroll
    for (int c = 0; c < 8; ++c) {
      const int pc = (half * 8 + c) ^ (dl & 15);
      *(uint4*)(vrow + c * 8) = *(const uint4*)(S + dl * 128 + pc * 8);
    }
  } else {
    // epilogue: C/D layout col=lane&15, row=quad*4+r  [verified m89/m91]
#pragma unroll
    for (int i = 0; i < 4; ++i)
#pragma unroll
      for (int j = 0; j < 4; ++j) {
        const int gn = nb * 128 + wn + j * 16 + l16;
        const float bv = bias[gn] * bscale;
#pragma unroll
        for (int r = 0; r < 4; ++r) {
          const int gm = mb * 128 + wm + i * 16 + quad * 4 + r;
          const float v = acc[i][j][r] + bv;
          if constexpr (sizeof(OT) == 2)
            D[(size_t)gm * 1024 + gn] = (OT)f2bf(v);
          else
            D[(size_t)gm * 1024 + gn] = (OT)v;
        }
      }
  }
}

__global__ __launch_bounds__(256) void qkv_kernel(
    const u16* __restrict__ xb, const u16* __restrict__ yb,
    const u16* __restrict__ Wqb, const u16* __restrict__ Wkb, const u16* __restrict__ Wvb,
    const float* __restrict__ bq, const float* __restrict__ bk, const float* __restrict__ bv,
    u16* __restrict__ qb, u16* __restrict__ kb, u16* __restrict__ vt) {
  const int mat = blockIdx.y >> 3;
  const int nb = blockIdx.y & 7;
  const int mb = blockIdx.x;
  if (mat == 0)      gemm_block_128<0, u16>(xb, Wqb, bq, QSC,  qb, mb, nb);
  else if (mat == 1) gemm_block_128<0, u16>(yb, Wkb, bk, 1.0f, kb, mb, nb);
  else               gemm_block_128<2, u16>(yb, Wvb, bv, 1.0f, vt, mb, nb);
}

__global__ __launch_bounds__(256) void oproj_kernel(
    const u16* __restrict__ ctx, const u16* __restrict__ Wob,
    const float* __restrict__ bo, float* __restrict__ out) {
  gemm_block_128<1, float>(ctx, Wob, bo, 1.0f, out, blockIdx.x, blockIdx.y);
}

// ---------- flash attention: 4 waves x 16 q-rows (64 q/block), KV tile = 64 ----
// Grid 1024 blocks = 4/CU (occupancy was the round-7/8 limiter). Computes S^T
// (A=K, B=Q). Bias tile and P tile SHARE one 8 KB LDS buffer BP[64q][64kv]:
// each lane's P-store address equals its bias-read address (same layout), and
// rows are wave-private after the staging barrier. LDS total 24 KB.
// No running max (scores bounded, exp2 domain; masked -> 2^-1.4e9 = 0).
// Row-sum via MFMA ones-column.
__global__ __launch_bounds__(256) void attn_kernel(
    const u16* __restrict__ qb, const u16* __restrict__ kb,
    const u16* __restrict__ vt, const u16* __restrict__ biasC,
    u16* __restrict__ ctx) {
  const int h = blockIdx.x;
  const int qblk = blockIdx.y;   // 0..31, 64 q each
  const int b = blockIdx.z;
  const int tid = threadIdx.x, w = tid >> 6, lane = tid & 63;
  const int quad = lane >> 4, l16 = lane & 15;
  const int q0 = qblk * 64;

  __shared__ __align__(16) u16 Ks[64 * 64];   // [kv][d]   swizzled rows, 8 KB
  __shared__ __align__(16) u16 Vs[64 * 64];   // [d][kv]   swizzled rows, 8 KB
  __shared__ __align__(16) u16 BP[64 * 64];   // bias/P [q][kv] swizzled, 8 KB

  const int qrow = w * 16 + l16;              // q-local row (wave-private set)
  const u16* qp = qb + (size_t)(b * SEQ + q0 + qrow) * D_MODEL + h * 64;
  const bf16x8 qf0 = ld_frag(qp + quad * 8);
  const bf16x8 qf1 = ld_frag(qp + 32 + quad * 8);

  // ones B-frag: row n==0 all 1.0 -> lane l16==0 holds ones
  bf16x8 onesf;
  {
    u16x8 t;
    const u16 ov = (l16 == 0) ? (u16)0x3F80 : (u16)0;
#pragma unroll
    for (int j = 0; j < 8; ++j) t[j] = ov;
    onesf = __builtin_bit_cast(bf16x8, t);
  }

  f32x4 O[4];
#pragma unroll
  for (int dt = 0; dt < 4; ++dt) O[dt] = f32x4{0.f, 0.f, 0.f, 0.f};
  f32x4 O4 = f32x4{0.f, 0.f, 0.f, 0.f};

  const int cidx = w * 64 + lane;
  const int bhalf = (quad & 1) * 4;           // b64 half-chunk offset (u16)

  for (int kt = 0; kt < 32; ++kt) {
    const int kv0 = kt * 64;

    __syncthreads();   // prior iteration's LDS reads complete
#pragma unroll
    for (int t = 0; t < 2; ++t) {
      const int idx = t * 256 + cidx;   // chunk 0..511
      const int row = idx >> 3;
      const int g = (idx & 7) ^ (row & 7);
      const size_t dst = (size_t)(t * 4 + w) * 1024;
      gld_lds16(kb + (size_t)(b * SEQ + kv0 + row) * D_MODEL + h * 64 + g * 8,
                (char*)Ks + dst);
      gld_lds16(vt + ((size_t)((b * NHEAD + h) * 64 + row)) * SEQ + kv0 + g * 8,
                (char*)Vs + dst);
      gld_lds16(biasC + (size_t)(b * SEQ + q0 + row) * SEQ + kv0 + g * 8,
                (char*)BP + dst);
    }
    __syncthreads();

    // S^T = K Q^T + bias (acc init from BP); z held in regs across nt
    f32x4 z[4];
#pragma unroll
    for (int nt = 0; nt < 4; ++nt) {
      const int kvl = nt * 16 + l16;
      const bf16x8 kf0 = ld_frag(Ks + kvl * 64 + ((quad ^ (kvl & 7)) * 8));
      const bf16x8 kf1 = ld_frag(Ks + kvl * 64 + (((4 + quad) ^ (kvl & 7)) * 8));
      const int ck = nt * 2 + (quad >> 1);
      const uint2 bw = *(const uint2*)(BP + qrow * 64 + ((ck ^ (qrow & 7)) * 8) + bhalf);
      f32x4 zz;
      zz[0] = __uint_as_float(bw.x << 16);
      zz[1] = __uint_as_float(bw.x & 0xffff0000u);
      zz[2] = __uint_as_float(bw.y << 16);
      zz[3] = __uint_as_float(bw.y & 0xffff0000u);
      zz = mfma16(kf0, qf0, zz);
      zz = mfma16(kf1, qf1, zz);
      z[nt] = zz;
    }
    // p = 2^S -> bf16, store back over the (consumed) bias locations
#pragma unroll
    for (int nt = 0; nt < 4; ++nt) {
      uint2 pv;
      pv.x = pack_rnd(ex2(z[nt][0]), ex2(z[nt][1]));
      pv.y = pack_rnd(ex2(z[nt][2]), ex2(z[nt][3]));
      const int ck = nt * 2 + (quad >> 1);
      *(uint2*)(BP + qrow * 64 + ((ck ^ (qrow & 7)) * 8) + bhalf) = pv;
    }

    // P A-frags (wave-private rows), then O += P V ; l += P * ones
    const bf16x8 pf0 = ld_frag(BP + qrow * 64 + ((quad ^ (qrow & 7)) * 8));
    const bf16x8 pf1 = ld_frag(BP + qrow * 64 + (((4 + quad) ^ (qrow & 7)) * 8));
#pragma unroll
    for (int dt = 0; dt < 4; ++dt) {
      const int vr = dt * 16 + l16;
      const bf16x8 vf0 = ld_frag(Vs + vr * 64 + ((quad ^ (vr & 7)) * 8));
      const bf16x8 vf1 = ld_frag(Vs + vr * 64 + (((4 + quad) ^ (vr & 7)) * 8));
      O[dt] = mfma16(pf0, vf0, O[dt]);
      O[dt] = mfma16(pf1, vf1, O[dt]);
    }
    O4 = mfma16(pf0, onesf, O4);
    O4 = mfma16(pf1, onesf, O4);
  }

  // l in col-0 lanes of each quad; epilogue ctx[b,q,h*64+d] = O / l
  float inv[4];
#pragma unroll
  for (int r = 0; r < 4; ++r)
    inv[r] = 1.0f / __shfl(O4[r], lane & 48, 64);

#pragma unroll
  for (int dt = 0; dt < 4; ++dt)
#pragma unroll
    for (int r = 0; r < 4; ++r) {
      const int gq = b * SEQ + q0 + w * 16 + quad * 4 + r;
      const int gd = h * 64 + dt * 16 + l16;
      ctx[(size_t)gq * D_MODEL + gd] = f2bf(O[dt][r] * inv[r]);
    }
}

// ---------- host ----------
extern "C" void kernel_launch(void* const* d_in, const int* in_sizes, int n_in,
                              void* d_out, int out_size, void* d_ws, size_t ws_size,
                              hipStream_t stream) {
  (void)in_sizes; (void)n_in; (void)out_size; (void)ws_size;
  const float* x    = (const float*)d_in[0];
  const float* y    = (const float*)d_in[1];
  const float* mask = (const float*)d_in[2];
  const float* Wq   = (const float*)d_in[3];
  const float* bq   = (const float*)d_in[4];
  const float* Wk   = (const float*)d_in[5];
  const float* bk   = (const float*)d_in[6];
  const float* Wv   = (const float*)d_in[7];
  const float* bv   = (const float*)d_in[8];
  const float* Wo   = (const float*)d_in[9];
  const float* bo   = (const float*)d_in[10];
  float* out = (float*)d_out;

  // 56 MB workspace (round-2-proven footprint), aliased by lifetime.
  const size_t M4 = (size_t)4096 * 1024;   // 4M u16 = 8 MB
  const size_t M1 = (size_t)1024 * 1024;   // 1M u16 = 2 MB
  u16* qbuf  = (u16*)d_ws;         // [0,8)   qkv -> attn
  u16* kbuf  = qbuf + M4;          // [8,16)  qkv -> attn
  u16* vt    = kbuf + M4;          // [16,24) qkv (transposed) -> attn
  u16* cbuf  = vt + M4;            // [24,32) attn -> oproj
  u16* wob   = cbuf + M4;          // [32,34) prep -> oproj
  u16* xb    = wob + M1;           // [34,42) cvt -> qkv (dead after)
  u16* yb    = xb + M4;            // [42,50) cvt -> qkv (dead after)
  u16* wqb   = yb + M4;            // [50,52) cvt -> qkv
  u16* wkb   = wqb + M1;           // [52,54)
  u16* wvb   = wkb + M1;           // [54,56)
  u16* biasC = xb;                 // 16 MB over xb+yb (written by prep, post-qkv)

  cvt_kernel<<<dim3(2048, 5, 1), 256, 0, stream>>>(x, y, Wq, Wk, Wv,
                                                   xb, yb, wqb, wkb, wvb);
  qkv_kernel<<<dim3(32, 24, 1), 256, 0, stream>>>(xb, yb, wqb, wkb, wvb,
                                                  bq, bk, bv, qbuf, kbuf, vt);
  prep_kernel<<<dim3(4608, 1, 1), 256, 0, stream>>>(mask, Wo, biasC, wob);
  attn_kernel<<<dim3(NHEAD, 32, 2), 256, 0, stream>>>(qbuf, kbuf, vt, biasC, cbuf);
  oproj_kernel<<<dim3(32, 8, 1), 256, 0, stream>>>(cbuf, wob, bo, out);
}

// Round 10
// 259.841 us; speedup vs baseline: 1.0407x; 1.0179x over previous
//
#include <hip/hip_runtime.h>
#include <cstdint>
#include <cstddef>

// ---------- types & helpers ----------
typedef __bf16 bf16x8 __attribute__((ext_vector_type(8)));
typedef float f32x4 __attribute__((ext_vector_type(4)));
typedef unsigned short u16;
typedef unsigned short u16x8 __attribute__((ext_vector_type(8)));
typedef unsigned int u32;

typedef __attribute__((address_space(1))) void gvoid_t;
typedef __attribute__((address_space(3))) void lvoid_t;

// async global->LDS, 16B per lane. LDS dest = wave-uniform base + lane*16.
__device__ __forceinline__ void gld_lds16(const void* g, void* l) {
  __builtin_amdgcn_global_load_lds((gvoid_t*)g, (lvoid_t*)l, 16, 0, 0);
}

__device__ __forceinline__ u16 f2bf(float f) {
  u32 u = __float_as_uint(f);
  u += 0x7fffu + ((u >> 16) & 1u);   // RNE
  return (u16)(u >> 16);
}
// packed f32x2 -> bf16x2 via v_perm_b32, half-up rounding: 3 VALU ops total
__device__ __forceinline__ u32 pack_rnd(float a, float b) {
  const u32 ua = __float_as_uint(a) + 0x8000u;
  const u32 ub = __float_as_uint(b) + 0x8000u;
  return __builtin_amdgcn_perm(ub, ua, 0x07060302u);  // [ub.hi16 : ua.hi16]
}
__device__ __forceinline__ bf16x8 ld_frag(const u16* p) {
  return __builtin_bit_cast(bf16x8, *(const uint4*)p);
}
__device__ __forceinline__ f32x4 mfma16(bf16x8 a, bf16x8 b, f32x4 c) {
  return __builtin_amdgcn_mfma_f32_16x16x32_bf16(a, b, c, 0, 0, 0);
}
// 2^x via v_exp_f32 (single instruction)
__device__ __forceinline__ float ex2(float x) {
  return __builtin_amdgcn_exp2f(x);
}

#define D_MODEL 1024
#define SEQ     2048
#define NHEAD   16
// 1/sqrt(HEAD) * log2(e): folded into Wq/bq so QK^T scores are in exp2 domain
#define QSC     0.1803368801f
#define MBIAS   (-1.4426950408e9f)   // -1e9 * log2(e)

// ---------- pre: all fp32->bf16 conversions in ONE launch ----------
// segments (blocks of 256 thr, 8 elems/thr):
//  [0,2048)      x   -> xb            (16 MB)
//  [2048,4096)   y   -> yb
//  [4096,4608)   Wq  -> wqb (scaled)
//  [4608,5120)   Wk  -> wkb
//  [5120,5632)   Wv  -> wvb
//  [5632,6144)   Wo  -> wob
//  [6144,10240)  mask-> biasC (in d_out!) = (1-m)*MBIAS
__global__ __launch_bounds__(256) void pre_kernel(
    const float* __restrict__ x,  const float* __restrict__ y,
    const float* __restrict__ wq, const float* __restrict__ wk,
    const float* __restrict__ wv, const float* __restrict__ wo,
    const float* __restrict__ mask,
    u16* __restrict__ xb, u16* __restrict__ yb,
    u16* __restrict__ wqb, u16* __restrict__ wkb,
    u16* __restrict__ wvb, u16* __restrict__ wob,
    u16* __restrict__ biasC) {
  const int bid = blockIdx.x;
  const float* src;
  u16* dst;
  int base;
  float sA = 1.0f, sB = 0.0f;        // out = f2bf(v*sA + sB)
  if (bid < 2048)      { src = x;    dst = xb;    base = 0; }
  else if (bid < 4096) { src = y;    dst = yb;    base = 2048; }
  else if (bid < 4608) { src = wq;   dst = wqb;   base = 4096; sA = QSC; }
  else if (bid < 5120) { src = wk;   dst = wkb;   base = 4608; }
  else if (bid < 5632) { src = wv;   dst = wvb;   base = 5120; }
  else if (bid < 6144) { src = wo;   dst = wob;   base = 5632; }
  else                 { src = mask; dst = biasC; base = 6144; sA = -MBIAS; sB = MBIAS; }
  const int i = (((bid - base) * 256) + threadIdx.x) * 8;
  const float4 a = *(const float4*)(src + i);
  const float4 b = *(const float4*)(src + i + 4);
  ushort4 lo, hi;
  lo.x = f2bf(a.x * sA + sB); lo.y = f2bf(a.y * sA + sB);
  lo.z = f2bf(a.z * sA + sB); lo.w = f2bf(a.w * sA + sB);
  hi.x = f2bf(b.x * sA + sB); hi.y = f2bf(b.y * sA + sB);
  hi.z = f2bf(b.z * sA + sB); hi.w = f2bf(b.w * sA + sB);
  *(ushort4*)(dst + i) = lo;
  *(ushort4*)(dst + i + 4) = hi;
}

// ---------- 128x128 BK=64 gemm_bt block (D = A @ W^T + bias*bscale) ----------
// MODE 0: D bf16 row-major [M,1024]; MODE 1: D fp32 row-major;
// MODE 2: D = vt, bf16 transposed [(b*16+h)*64+d][s] via LDS transpose epilogue.
template <int MODE, typename OT>
__device__ __forceinline__ void gemm_block_128(const u16* __restrict__ A,
                                               const u16* __restrict__ W,
                                               const float* __restrict__ bias,
                                               float bscale,
                                               OT* __restrict__ D,
                                               int mb, int nb) {
  __shared__ __align__(16) u16 S[16384];     // Asl(8K u16) + Bsl(8K u16)
  u16* Asl = S;
  u16* Bsl = S + 8192;
  const int tid = threadIdx.x;
  const int w = tid >> 6, lane = tid & 63, quad = lane >> 4, l16 = lane & 15;
  const int wm = (w & 1) * 64, wn = (w >> 1) * 64;
  const int cidx = w * 64 + lane;

  f32x4 acc[4][4];
#pragma unroll
  for (int i = 0; i < 4; ++i)
#pragma unroll
    for (int j = 0; j < 4; ++j) acc[i][j] = f32x4{0.f, 0.f, 0.f, 0.f};

  for (int k0 = 0; k0 < 1024; k0 += 64) {
    __syncthreads();
#pragma unroll
    for (int t = 0; t < 4; ++t) {
      const int idx = t * 256 + cidx;          // 16B-chunk id, 0..1023
      const int row = idx >> 3;                // 8 chunks per 64-elem row
      const int g = (idx & 7) ^ (row & 7);     // swizzled source chunk
      const size_t dst = (size_t)(t * 4 + w) * 1024;
      gld_lds16(A + (size_t)(mb * 128 + row) * 1024 + k0 + g * 8, (char*)Asl + dst);
      gld_lds16(W + (size_t)(nb * 128 + row) * 1024 + k0 + g * 8, (char*)Bsl + dst);
    }
    __syncthreads();

#pragma unroll
    for (int kk = 0; kk < 2; ++kk) {
      bf16x8 af[4], bfr[4];
#pragma unroll
      for (int i = 0; i < 4; ++i) {
        const int ar = wm + i * 16 + l16;
        const int br = wn + i * 16 + l16;
        af[i]  = ld_frag(Asl + ar * 64 + (((kk * 4 + quad) ^ (ar & 7)) * 8));
        bfr[i] = ld_frag(Bsl + br * 64 + (((kk * 4 + quad) ^ (br & 7)) * 8));
      }
#pragma unroll
      for (int i = 0; i < 4; ++i)
#pragma unroll
        for (int j = 0; j < 4; ++j) acc[i][j] = mfma16(af[i], bfr[j], acc[i][j]);
    }
  }

  if constexpr (MODE == 2) {
    // transposed epilogue: acc tile [128 s][128 d] -> LDS [d][s] -> vt rows
    __syncthreads();   // all waves done with Asl/Bsl frag reads
#pragma unroll
    for (int i = 0; i < 4; ++i)
#pragma unroll
      for (int j = 0; j < 4; ++j) {
        const int dl = wn + j * 16 + l16;
        const float bv = bias[nb * 128 + dl];
        const int sx = (wm + i * 16 + quad * 4) ^ ((dl & 15) << 3);
        uint2 pv;
        pv.x = (u32)f2bf(acc[i][j][0] + bv) | ((u32)f2bf(acc[i][j][1] + bv) << 16);
        pv.y = (u32)f2bf(acc[i][j][2] + bv) | ((u32)f2bf(acc[i][j][3] + bv) << 16);
        *(uint2*)(S + dl * 128 + sx) = pv;
      }
    __syncthreads();
    const int dl = tid >> 1, half = tid & 1;
    const int bb = mb >> 4, s0 = (mb & 15) * 128;
    u16* vrow = (u16*)D + (size_t)(bb * 1024 + nb * 128 + dl) * SEQ + s0 + half * 64;
#pragma unroll
    for (int c = 0; c < 8; ++c) {
      const int pc = (half * 8 + c) ^ (dl & 15);
      *(uint4*)(vrow + c * 8) = *(const uint4*)(S + dl * 128 + pc * 8);
    }
  } else {
    // epilogue: C/D layout col=lane&15, row=quad*4+r  [verified m89/m91]
#pragma unroll
    for (int i = 0; i < 4; ++i)
#pragma unroll
      for (int j = 0; j < 4; ++j) {
        const int gn = nb * 128 + wn + j * 16 + l16;
        const float bv = bias[gn] * bscale;
#pragma unroll
        for (int r = 0; r < 4; ++r) {
          const int gm = mb * 128 + wm + i * 16 + quad * 4 + r;
          const float v = acc[i][j][r] + bv;
          if constexpr (sizeof(OT) == 2)
            D[(size_t)gm * 1024 + gn] = (OT)f2bf(v);
          else
            D[(size_t)gm * 1024 + gn] = (OT)v;
        }
      }
  }
}

__global__ __launch_bounds__(256) void qkv_kernel(
    const u16* __restrict__ xb, const u16* __restrict__ yb,
    const u16* __restrict__ Wqb, const u16* __restrict__ Wkb, const u16* __restrict__ Wvb,
    const float* __restrict__ bq, const float* __restrict__ bk, const float* __restrict__ bv,
    u16* __restrict__ qb, u16* __restrict__ kb, u16* __restrict__ vt) {
  const int mat = blockIdx.y >> 3;
  const int nb = blockIdx.y & 7;
  const int mb = blockIdx.x;
  if (mat == 0)      gemm_block_128<0, u16>(xb, Wqb, bq, QSC,  qb, mb, nb);
  else if (mat == 1) gemm_block_128<0, u16>(yb, Wkb, bk, 1.0f, kb, mb, nb);
  else               gemm_block_128<2, u16>(yb, Wvb, bv, 1.0f, vt, mb, nb);
}

__global__ __launch_bounds__(256) void oproj_kernel(
    const u16* __restrict__ ctx, const u16* __restrict__ Wob,
    const float* __restrict__ bo, float* __restrict__ out) {
  gemm_block_128<1, float>(ctx, Wob, bo, 1.0f, out, blockIdx.x, blockIdx.y);
}

// ---------- flash attention: 4 waves x 16 q-rows (64 q/block), KV tile = 64 ----
// Grid 1024 blocks = 4/CU. Computes S^T (A=K, B=Q). Bias tile and P tile share
// one 8 KB LDS buffer BP[64q][64kv] (each lane's P-store address equals its
// bias-read address; rows wave-private after the staging barrier). LDS 24 KB.
// No running max (scores bounded, exp2 domain; masked -> 2^-1.4e9 = 0).
// Row-sum via MFMA ones-column. Staging pointers loop-carried (+= stride).
__global__ __launch_bounds__(256) void attn_kernel(
    const u16* __restrict__ qb, const u16* __restrict__ kb,
    const u16* __restrict__ vt, const u16* __restrict__ biasC,
    u16* __restrict__ ctx) {
  const int h = blockIdx.x;
  const int qblk = blockIdx.y;   // 0..31, 64 q each
  const int b = blockIdx.z;
  const int tid = threadIdx.x, w = tid >> 6, lane = tid & 63;
  const int quad = lane >> 4, l16 = lane & 15;
  const int q0 = qblk * 64;

  __shared__ __align__(16) u16 Ks[64 * 64];   // [kv][d]   swizzled rows, 8 KB
  __shared__ __align__(16) u16 Vs[64 * 64];   // [d][kv]   swizzled rows, 8 KB
  __shared__ __align__(16) u16 BP[64 * 64];   // bias/P [q][kv] swizzled, 8 KB

  const int qrow = w * 16 + l16;              // q-local row (wave-private set)
  const u16* qp = qb + (size_t)(b * SEQ + q0 + qrow) * D_MODEL + h * 64;
  const bf16x8 qf0 = ld_frag(qp + quad * 8);
  const bf16x8 qf1 = ld_frag(qp + 32 + quad * 8);

  // ones B-frag: row n==0 all 1.0 -> lane l16==0 holds ones
  bf16x8 onesf;
  {
    u16x8 t;
    const u16 ov = (l16 == 0) ? (u16)0x3F80 : (u16)0;
#pragma unroll
    for (int j = 0; j < 8; ++j) t[j] = ov;
    onesf = __builtin_bit_cast(bf16x8, t);
  }

  f32x4 O[4];
#pragma unroll
  for (int dt = 0; dt < 4; ++dt) O[dt] = f32x4{0.f, 0.f, 0.f, 0.f};
  f32x4 O4 = f32x4{0.f, 0.f, 0.f, 0.f};

  const int cidx = w * 64 + lane;
  const int bhalf = (quad & 1) * 4;           // b64 half-chunk offset (u16)

  // loop-carried staging pointers (t=0 and t=1 chunk of each stream)
  const int r0 = cidx >> 3,        g0 = (cidx & 7) ^ (r0 & 7);
  const int r1 = (256 + cidx) >> 3, g1 = ((256 + cidx) & 7) ^ (r1 & 7);
  const u16* kp0 = kb + (size_t)(b * SEQ + r0) * D_MODEL + h * 64 + g0 * 8;
  const u16* kp1 = kb + (size_t)(b * SEQ + r1) * D_MODEL + h * 64 + g1 * 8;
  const u16* vp0 = vt + ((size_t)((b * NHEAD + h) * 64 + r0)) * SEQ + g0 * 8;
  const u16* vp1 = vt + ((size_t)((b * NHEAD + h) * 64 + r1)) * SEQ + g1 * 8;
  const u16* bp0 = biasC + (size_t)(b * SEQ + q0 + r0) * SEQ + g0 * 8;
  const u16* bp1 = biasC + (size_t)(b * SEQ + q0 + r1) * SEQ + g1 * 8;
  char* ld0 = (char*)nullptr;
  const size_t dst0 = (size_t)w * 1024;
  const size_t dst1 = (size_t)(4 + w) * 1024;
  (void)ld0;

  for (int kt = 0; kt < 32; ++kt) {
    __syncthreads();   // prior iteration's LDS reads complete
    gld_lds16(kp0, (char*)Ks + dst0);
    gld_lds16(kp1, (char*)Ks + dst1);
    gld_lds16(vp0, (char*)Vs + dst0);
    gld_lds16(vp1, (char*)Vs + dst1);
    gld_lds16(bp0, (char*)BP + dst0);
    gld_lds16(bp1, (char*)BP + dst1);
    kp0 += 64 * D_MODEL; kp1 += 64 * D_MODEL;   // next 64 kv rows
    vp0 += 64;           vp1 += 64;             // next 64 kv cols
    bp0 += 64;           bp1 += 64;
    __syncthreads();

    // S^T = K Q^T + bias (acc init from BP); z held in regs across nt
    f32x4 z[4];
#pragma unroll
    for (int nt = 0; nt < 4; ++nt) {
      const int kvl = nt * 16 + l16;
      const bf16x8 kf0 = ld_frag(Ks + kvl * 64 + ((quad ^ (kvl & 7)) * 8));
      const bf16x8 kf1 = ld_frag(Ks + kvl * 64 + (((4 + quad) ^ (kvl & 7)) * 8));
      const int ck = nt * 2 + (quad >> 1);
      const uint2 bw = *(const uint2*)(BP + qrow * 64 + ((ck ^ (qrow & 7)) * 8) + bhalf);
      f32x4 zz;
      zz[0] = __uint_as_float(bw.x << 16);
      zz[1] = __uint_as_float(bw.x & 0xffff0000u);
      zz[2] = __uint_as_float(bw.y << 16);
      zz[3] = __uint_as_float(bw.y & 0xffff0000u);
      zz = mfma16(kf0, qf0, zz);
      zz = mfma16(kf1, qf1, zz);
      z[nt] = zz;
    }
    // p = 2^S -> bf16, store back over the (consumed) bias locations
#pragma unroll
    for (int nt = 0; nt < 4; ++nt) {
      uint2 pv;
      pv.x = pack_rnd(ex2(z[nt][0]), ex2(z[nt][1]));
      pv.y = pack_rnd(ex2(z[nt][2]), ex2(z[nt][3]));
      const int ck = nt * 2 + (quad >> 1);
      *(uint2*)(BP + qrow * 64 + ((ck ^ (qrow & 7)) * 8) + bhalf) = pv;
    }

    // P A-frags (wave-private rows), then O += P V ; l += P * ones
    const bf16x8 pf0 = ld_frag(BP + qrow * 64 + ((quad ^ (qrow & 7)) * 8));
    const bf16x8 pf1 = ld_frag(BP + qrow * 64 + (((4 + quad) ^ (qrow & 7)) * 8));
#pragma unroll
    for (int dt = 0; dt < 4; ++dt) {
      const int vr = dt * 16 + l16;
      const bf16x8 vf0 = ld_frag(Vs + vr * 64 + ((quad ^ (vr & 7)) * 8));
      const bf16x8 vf1 = ld_frag(Vs + vr * 64 + (((4 + quad) ^ (vr & 7)) * 8));
      O[dt] = mfma16(pf0, vf0, O[dt]);
      O[dt] = mfma16(pf1, vf1, O[dt]);
    }
    O4 = mfma16(pf0, onesf, O4);
    O4 = mfma16(pf1, onesf, O4);
  }

  // l in col-0 lanes of each quad; epilogue ctx[b,q,h*64+d] = O / l
  float inv[4];
#pragma unroll
  for (int r = 0; r < 4; ++r)
    inv[r] = 1.0f / __shfl(O4[r], lane & 48, 64);

#pragma unroll
  for (int dt = 0; dt < 4; ++dt)
#pragma unroll
    for (int r = 0; r < 4; ++r) {
      const int gq = b * SEQ + q0 + w * 16 + quad * 4 + r;
      const int gd = h * 64 + dt * 16 + l16;
      ctx[(size_t)gq * D_MODEL + gd] = f2bf(O[dt][r] * inv[r]);
    }
}

// ---------- host ----------
extern "C" void kernel_launch(void* const* d_in, const int* in_sizes, int n_in,
                              void* d_out, int out_size, void* d_ws, size_t ws_size,
                              hipStream_t stream) {
  (void)in_sizes; (void)n_in; (void)out_size; (void)ws_size;
  const float* x    = (const float*)d_in[0];
  const float* y    = (const float*)d_in[1];
  const float* mask = (const float*)d_in[2];
  const float* Wq   = (const float*)d_in[3];
  const float* bq   = (const float*)d_in[4];
  const float* Wk   = (const float*)d_in[5];
  const float* bk   = (const float*)d_in[6];
  const float* Wv   = (const float*)d_in[7];
  const float* bv   = (const float*)d_in[8];
  const float* Wo   = (const float*)d_in[9];
  const float* bo   = (const float*)d_in[10];
  float* out = (float*)d_out;

  // 56 MB workspace (round-2-proven footprint), aliased by lifetime.
  // biasC (16 MB) lives in d_out: written by pre, read by attn, then d_out is
  // fully overwritten by oproj (stream-ordered).
  const size_t M4 = (size_t)4096 * 1024;   // 4M u16 = 8 MB
  const size_t M1 = (size_t)1024 * 1024;   // 1M u16 = 2 MB
  u16* qbuf  = (u16*)d_ws;         // [0,8)   qkv -> attn
  u16* kbuf  = qbuf + M4;          // [8,16)  qkv -> attn
  u16* vt    = kbuf + M4;          // [16,24) qkv (transposed) -> attn
  u16* cbuf  = vt + M4;            // [24,32) attn -> oproj
  u16* wob   = cbuf + M4;          // [32,34) pre -> oproj
  u16* xb    = wob + M1;           // [34,42) pre -> qkv
  u16* yb    = xb + M4;            // [42,50) pre -> qkv
  u16* wqb   = yb + M4;            // [50,52) pre -> qkv
  u16* wkb   = wqb + M1;           // [52,54)
  u16* wvb   = wkb + M1;           // [54,56)
  u16* biasC = (u16*)d_out;        // 16 MB, pre -> attn

  pre_kernel<<<dim3(10240, 1, 1), 256, 0, stream>>>(
      x, y, Wq, Wk, Wv, Wo, mask, xb, yb, wqb, wkb, wvb, wob, biasC);
  qkv_kernel<<<dim3(32, 24, 1), 256, 0, stream>>>(xb, yb, wqb, wkb, wvb,
                                                  bq, bk, bv, qbuf, kbuf, vt);
  attn_kernel<<<dim3(NHEAD, 32, 2), 256, 0, stream>>>(qbuf, kbuf, vt, biasC, cbuf);
  oproj_kernel<<<dim3(32, 8, 1), 256, 0, stream>>>(cbuf, wob, bo, out);
}